// Round 17
// baseline (74.149 us; speedup 1.0000x reference)
//
#include <hip/hip_runtime.h>

#define D 8
#define NE 4
#define NS 3
#define NI 5
#define LN_EPS 1e-5f

// wlds: per-stage blocks of 176 floats:
//   +0   W1   (64, [d][k], shared)
//   +64  W2P  (64, parity-permuted: [pp][d][j], j in {own0,own1,oth0,oth1})
//   +128 C    (32, n-paired [nn][d][2]; lane reads nn=p sub-block)
//   +160 B1   (8)
//   +168 B2P  (8, parity-permuted [pp][j])
// then Wproj (NS*512) at 528, LN (16) at 2064.
#define STAGE_STRIDE 176
#define SOFF_W1  0
#define SOFF_W2P 64
#define SOFF_C   128
#define SOFF_B1  160
#define SOFF_B2P 168
#define OFF_WP   528
#define OFF_LN   2064
#define WLDS_SIZE 2080

typedef float f2 __attribute__((ext_vector_type(2)));
typedef float f4 __attribute__((ext_vector_type(4)));

__device__ __forceinline__ f2 max2(f2 a, f2 b) { return __builtin_elementwise_max(a, b); }
__device__ __forceinline__ f2 bc(float s) { return (f2){s, s}; }

// forced VOP3P packed-f32 FMA; op_sel gives free src1 half-broadcast
__device__ __forceinline__ void pk_fma_lo(f2& acc, f2 a, f2 b) {
    asm("v_pk_fma_f32 %0, %1, %2, %0 op_sel:[0,0,0] op_sel_hi:[1,0,1]"
        : "+v"(acc) : "v"(a), "v"(b));
}
__device__ __forceinline__ void pk_fma_hi(f2& acc, f2 a, f2 b) {
    asm("v_pk_fma_f32 %0, %1, %2, %0 op_sel:[0,1,0] op_sel_hi:[1,1,1]"
        : "+v"(acc) : "v"(a), "v"(b));
}
__device__ __forceinline__ void pk_fma_ee(f2& acc, f2 a, f2 b) {
    asm("v_pk_fma_f32 %0, %1, %2, %0"
        : "+v"(acc) : "v"(a), "v"(b));
}

// lane <-> lane^1 exchange via DPP quad_perm [1,0,3,2]
__device__ __forceinline__ float xor1f(float x) {
    int i = __builtin_bit_cast(int, x);
    i = __builtin_amdgcn_mov_dpp(i, 0xB1, 0xF, 0xF, true);
    return __builtin_bit_cast(float, i);
}
__device__ __forceinline__ f2 xor1f2(f2 x) { return (f2){ xor1f(x.x), xor1f(x.y) }; }

// ---------------------------------------------------------------------------
// Setup kernel: C in n-PAIRED layout: C[s*32 + ((n>>1)*8 + d)*2 + (n&1)]
// ---------------------------------------------------------------------------
__global__ void precompute_C_kernel(const float* __restrict__ Bmat,
                                    const float* __restrict__ Wproj,
                                    const float* __restrict__ bproj,
                                    float* __restrict__ C) {
    int idx = threadIdx.x;
    if (idx >= NS * NE * D) return;
    int s = idx / (NE * D);
    int rem = idx % (NE * D);
    int n = rem / D;
    int d = rem % D;
    const float* bm = Bmat + ((size_t)s * NE + n) * 64;
    const float* wp = Wproj + ((size_t)s * D + d) * 64;
    float acc = bproj[s * D + d];
    #pragma unroll
    for (int k = 0; k < 64; ++k) acc += bm[k] * wp[k];
    C[s * 32 + ((n >> 1) * 8 + d) * 2 + (n & 1)] = acc;
}

__device__ __forceinline__ float fast_tanh(float x) {
    float e = __expf(2.f * x);
    return 1.f - 2.f * __builtin_amdgcn_rcpf(e + 1.f);
}

__device__ __forceinline__ f4 ld4(const float* p) {
    return *reinterpret_cast<const f4*>(p);
}

// ---------------------------------------------------------------------------
// Main kernel: TWO lanes per row, split by EXPERT pair (lane parity p owns
// experts {2p,2p+1}); f2 packs the two owned experts. H/routing/softmax are
// per-expert -> NO exchange; only the E-update needs the partner's H
// (8 xor1f2 = 16 DPP/iter; R11's d-split needed ~48 + duplicated softmax).
// Static e-indexing via parity-permuted W2P/B2P in LDS (softmax is
// order-agnostic). t[8][8] per lane in registers (duplicated compute).
// 262144 threads -> 4 waves/SIMD; (256,2) keeps the allocator in its clean
// 128-budget mode (R2/R9/R15-proven) and VGPR<=128 allows the full 4 waves.
// ---------------------------------------------------------------------------
__global__ __launch_bounds__(256, 2) void whisp_kernel(
    const float* __restrict__ cl, const float* __restrict__ cd,
    const float* __restrict__ re_log, const float* __restrict__ mach,
    const float* __restrict__ alpha, const float* __restrict__ u,
    const float* __restrict__ We, const float* __restrict__ be,
    const float* __restrict__ Wproj,
    const float* __restrict__ Wr1, const float* __restrict__ br1,
    const float* __restrict__ Wr2, const float* __restrict__ br2,
    const float* __restrict__ ln_g, const float* __restrict__ ln_b,
    const float* __restrict__ Wout, const float* __restrict__ bout,
    const float* __restrict__ fg, const float* __restrict__ fb,
    const float* __restrict__ Wcst, const float* __restrict__ bcst,
    const float* __restrict__ Wcl, const float* __restrict__ bcl,
    const float* __restrict__ Cpre,
    float* __restrict__ out, int B)
{
    __shared__ __align__(16) float wlds[WLDS_SIZE];   // 8320 B
    __shared__ __align__(16) f4 ubuf[2 * 128];        // 4096 B (per-row uu)
    __shared__ float souts[128 * 19];                 // 9728 B

    const int tid = threadIdx.x;
    const int p   = tid & 1;            // expert-pair parity
    const int rl  = tid >> 1;           // row within block (0..127)
    const int row0 = blockIdx.x * 128 + rl;
    const bool active = (row0 < B);
    const int row = active ? row0 : (B - 1);
    const int eb  = 2 * p;              // own expert base

    // ---- stage weights into per-stage LDS blocks ----
    for (int i = tid; i < NS * 64; i += 256) {         // W1 natural
        int s = i / 64, j = i % 64;
        wlds[s * STAGE_STRIDE + SOFF_W1 + j] = Wr1[i];
    }
    for (int i = tid; i < NS * 64; i += 256) {         // W2P parity-permuted
        int s = i / 64, j = i % 64, pp = j / 32, r = j % 32, d = r / 4, jj = r % 4;
        int e = (jj < 2) ? (2 * pp + jj) : (2 * (1 - pp) + (jj - 2));
        wlds[s * STAGE_STRIDE + SOFF_W2P + j] = Wr2[s * 32 + e * 8 + d];
    }
    for (int i = tid; i < NS * 32; i += 256) {         // C (n-paired)
        int s = i / 32, j = i % 32;
        wlds[s * STAGE_STRIDE + SOFF_C + j] = Cpre[i];
    }
    for (int i = tid; i < NS * 8; i += 256) {          // B1
        int s = i / 8, j = i % 8;
        wlds[s * STAGE_STRIDE + SOFF_B1 + j] = br1[i];
    }
    for (int i = tid; i < NS * 8; i += 256) {          // B2P parity-permuted
        int s = i / 8, j = i % 8, pp = j / 4, jj = j % 4;
        int e = (jj < 2) ? (2 * pp + jj) : (2 * (1 - pp) + (jj - 2));
        wlds[s * STAGE_STRIDE + SOFF_B2P + j] = br2[s * 4 + e];
    }
    for (int i = tid; i < 1536; i += 256) wlds[OFF_WP + i] = Wproj[i];
    for (int i = tid; i < 8; i += 256) { wlds[OFF_LN + i] = ln_g[i]; wlds[OFF_LN + 8 + i] = ln_b[i]; }

    // ---- per-row inputs; uu stashed per-row in LDS (both lanes share) ----
    {
        const f4* up = reinterpret_cast<const f4*>(u + (size_t)row * D);
        ubuf[p * 128 + rl] = up[p];    // lane p loads f4 #p: fully coalesced
    }
    float xa = (p ? re_log : cl)[row];   // input for expert eb
    float xb = (p ? mach   : cd)[row];   // input for expert eb+1
    float al = alpha[row];

    // ---- embedding for OWN experts only: E2[d] = (E[eb][d], E[eb+1][d]) ----
    f2 E2[D];
    #pragma unroll
    for (int d = 0; d < D; ++d) {
        float pa = We[eb * 16 + d * 2] * xa + We[eb * 16 + d * 2 + 1] * al + be[eb * 8 + d];
        float pb = We[(eb + 1) * 16 + d * 2] * xb + We[(eb + 1) * 16 + d * 2 + 1] * al + be[(eb + 1) * 8 + d];
        E2[d] = (f2){ fast_tanh(pa), fast_tanh(pb) };
    }

    __syncthreads();   // wlds + ubuf ready

    int zero = 0;      // opaque 0: blocks LICM of broadcast weight loads

    // ---- outer stages ----
    #pragma unroll 1
    for (int s = 0; s < NS; ++s) {
        const float* stage_base = wlds + s * STAGE_STRIDE;

        // full t in registers per lane: tp[d][kp] = (t[d][2kp], t[d][2kp+1])
        f2 tp[D][4];
        {
            f4 uq0 = ubuf[rl], uq1 = ubuf[128 + rl];
            f2 uu2[4] = { uq0.lo, uq0.hi, uq1.lo, uq1.hi };
            const float* Wp = wlds + OFF_WP + s * 512;
            #pragma unroll
            for (int d = 0; d < D; ++d) {
                #pragma unroll
                for (int kp = 0; kp < 4; ++kp) {
                    int i0 = 2 * kp, i1 = 2 * kp + 1;
                    f4 a0 = ld4(Wp + d * 64 + i0 * 8);
                    f4 a1 = ld4(Wp + d * 64 + i0 * 8 + 4);
                    f4 b0 = ld4(Wp + d * 64 + i1 * 8);
                    f4 b1 = ld4(Wp + d * 64 + i1 * 8 + 4);
                    f2 accA = uu2[0] * a0.lo;
                    pk_fma_ee(accA, uu2[1], a0.hi);
                    pk_fma_ee(accA, uu2[2], a1.lo);
                    pk_fma_ee(accA, uu2[3], a1.hi);
                    f2 accB = uu2[0] * b0.lo;
                    pk_fma_ee(accB, uu2[1], b0.hi);
                    pk_fma_ee(accB, uu2[2], b1.lo);
                    pk_fma_ee(accB, uu2[3], b1.hi);
                    tp[d][kp] = (f2){ accA.x + accA.y, accB.x + accB.y };
                }
            }
        }

        #pragma unroll 1
        for (int it = 0; it < NI; ++it) {
            asm volatile("" : "+v"(zero));
            const float* sb = stage_base + zero;

            // H for OWN experts: init from own C sub-block (nn = p)
            f2 H2[D];
            #pragma unroll
            for (int dp = 0; dp < 4; ++dp) {
                f4 cq = ld4(sb + SOFF_C + p * 16 + dp * 4);
                H2[2 * dp]     = cq.lo;
                H2[2 * dp + 1] = cq.hi;
            }
            #pragma unroll
            for (int d = 0; d < D; ++d) {
                f2 acc = H2[d];
                pk_fma_lo(acc, E2[0], tp[d][0]);
                pk_fma_hi(acc, E2[1], tp[d][0]);
                pk_fma_lo(acc, E2[2], tp[d][1]);
                pk_fma_hi(acc, E2[3], tp[d][1]);
                pk_fma_lo(acc, E2[4], tp[d][2]);
                pk_fma_hi(acc, E2[5], tp[d][2]);
                pk_fma_lo(acc, E2[6], tp[d][3]);
                pk_fma_hi(acc, E2[7], tp[d][3]);
                H2[d] = acc;
            }

            // lg init from parity-permuted B2P: order (own0, own1, oth0, oth1)
            f2 lg2[NE];
            {
                f4 b2q = ld4(sb + SOFF_B2P + p * 4);
                lg2[0] = bc(b2q.x); lg2[1] = bc(b2q.y);
                lg2[2] = bc(b2q.z); lg2[3] = bc(b2q.w);
            }

            // fused routing for OWN experts (W1 shared; W2P parity-permuted)
            #pragma unroll
            for (int d = 0; d < D; ++d) {
                f4 wa = ld4(sb + SOFF_W1 + d * 8);
                f4 wb = ld4(sb + SOFF_W1 + d * 8 + 4);
                f4 w2 = ld4(sb + SOFF_W2P + p * 32 + d * 4);
                float b1d = sb[SOFF_B1 + d];
                f2 acc = bc(b1d);
                pk_fma_lo(acc, H2[0], wa.lo);
                pk_fma_hi(acc, H2[1], wa.lo);
                pk_fma_lo(acc, H2[2], wa.hi);
                pk_fma_hi(acc, H2[3], wa.hi);
                pk_fma_lo(acc, H2[4], wb.lo);
                pk_fma_hi(acc, H2[5], wb.lo);
                pk_fma_lo(acc, H2[6], wb.hi);
                pk_fma_hi(acc, H2[7], wb.hi);
                f2 r2 = max2(acc, bc(0.f));
                pk_fma_lo(lg2[0], r2, w2.lo);
                pk_fma_hi(lg2[1], r2, w2.lo);
                pk_fma_lo(lg2[2], r2, w2.hi);
                pk_fma_hi(lg2[3], r2, w2.hi);
            }

            // packed softmax over the 4 targets (order-agnostic)
            f2 sm2[NE];
            {
                f2 m2 = max2(max2(lg2[0], lg2[1]), max2(lg2[2], lg2[3]));
                f2 e0 = lg2[0] - m2, e1 = lg2[1] - m2, e2 = lg2[2] - m2, e3 = lg2[3] - m2;
                f2 x0 = (f2){ __expf(e0.x), __expf(e0.y) };
                f2 x1 = (f2){ __expf(e1.x), __expf(e1.y) };
                f2 x2 = (f2){ __expf(e2.x), __expf(e2.y) };
                f2 x3 = (f2){ __expf(e3.x), __expf(e3.y) };
                f2 s2 = (x0 + x1) + (x2 + x3);
                f2 inv2 = (f2){ __builtin_amdgcn_rcpf(s2.x), __builtin_amdgcn_rcpf(s2.y) };
                sm2[0] = x0 * inv2; sm2[1] = x1 * inv2;
                sm2[2] = x2 * inv2; sm2[3] = x3 * inv2;
            }

            // partner's H (other expert pair) via DPP
            f2 Ho2[D];
            #pragma unroll
            for (int d = 0; d < D; ++d) Ho2[d] = xor1f2(H2[d]);

            // E2[d] += sm2[0]*H_own0 + sm2[1]*H_own1 + sm2[2]*H_oth0 + sm2[3]*H_oth1
            #pragma unroll
            for (int d = 0; d < D; ++d) {
                f2 acc = E2[d];
                pk_fma_lo(acc, sm2[0], H2[d]);
                pk_fma_hi(acc, sm2[1], H2[d]);
                pk_fma_lo(acc, sm2[2], Ho2[d]);
                pk_fma_hi(acc, sm2[3], Ho2[d]);
                E2[d] = acc;
            }
        }

        // post-stage LayerNorm for own experts (all lane-local)
        float lngv[8], lnbv[8];
        {
            f4 g0 = ld4(wlds + OFF_LN),     g1 = ld4(wlds + OFF_LN + 4);
            f4 b0 = ld4(wlds + OFF_LN + 8), b1 = ld4(wlds + OFF_LN + 12);
            lngv[0]=g0.x; lngv[1]=g0.y; lngv[2]=g0.z; lngv[3]=g0.w;
            lngv[4]=g1.x; lngv[5]=g1.y; lngv[6]=g1.z; lngv[7]=g1.w;
            lnbv[0]=b0.x; lnbv[1]=b0.y; lnbv[2]=b0.z; lnbv[3]=b0.w;
            lnbv[4]=b1.x; lnbv[5]=b1.y; lnbv[6]=b1.z; lnbv[7]=b1.w;
        }
        {
            f2 s2 = (E2[0] + E2[1]) + (E2[2] + E2[3]);
            s2 = s2 + (E2[4] + E2[5]) + (E2[6] + E2[7]);
            f2 m2 = s2 * bc(0.125f);
            f2 v2 = bc(0.f);
            #pragma unroll
            for (int d = 0; d < D; ++d) { f2 c = E2[d] - m2; pk_fma_ee(v2, c, c); }
            v2 = v2 * bc(0.125f);
            f2 inv2 = (f2){ __builtin_amdgcn_rsqf(v2.x + LN_EPS),
                            __builtin_amdgcn_rsqf(v2.y + LN_EPS) };
            #pragma unroll
            for (int d = 0; d < D; ++d) {
                f2 r = bc(lnbv[d]);
                pk_fma_ee(r, (E2[d] - m2) * inv2, bc(lngv[d]));
                E2[d] = r;
            }
        }
    }

    // ---- final mixing: partial logits over own experts, DPP-reduce ----
    float w0, w1, w2, w3;
    {
        float lgf[NE];
        #pragma unroll
        for (int e = 0; e < NE; ++e) {
            float a0 = 0.f, a1 = 0.f;
            #pragma unroll
            for (int d = 0; d < D; ++d) {
                a0 = fmaf(E2[d].x, Wout[e * 32 + eb * 8 + d],     a0);
                a1 = fmaf(E2[d].y, Wout[e * 32 + eb * 8 + 8 + d], a1);
            }
            float part = a0 + a1;
            lgf[e] = part + xor1f(part) + bout[e];
        }
        float mx = fmaxf(fmaxf(lgf[0], lgf[1]), fmaxf(lgf[2], lgf[3]));
        w0 = __expf(lgf[0] - mx); w1 = __expf(lgf[1] - mx);
        w2 = __expf(lgf[2] - mx); w3 = __expf(lgf[3] - mx);
        float winv = __builtin_amdgcn_rcpf((w0 + w1) + (w2 + w3));
        w0 *= winv; w1 *= winv; w2 *= winv; w3 *= winv;
    }

    // z[d] = sum_n w_n E[n][d]: own partial + DPP reduce (full z in both lanes)
    float z[D];
    {
        float wo0 = p ? w2 : w0;
        float wo1 = p ? w3 : w1;
        #pragma unroll
        for (int d = 0; d < D; ++d) {
            float zp = fmaf(wo0, E2[d].x, wo1 * E2[d].y);
            z[d] = zp + xor1f(zp);
        }
    }
    {
        float zm = 0.f;
        #pragma unroll
        for (int d = 0; d < D; ++d) zm += z[d];
        zm *= (1.f / D);
        float zv = 0.f;
        #pragma unroll
        for (int d = 0; d < D; ++d) { float c = z[d] - zm; zv = fmaf(c, c, zv); }
        zv *= (1.f / D);
        float zinv = __builtin_amdgcn_rsqf(zv + LN_EPS);
        #pragma unroll
        for (int d = 0; d < D; ++d)
            z[d] = (z[d] - zm) * zinv * fg[d] + fb[d];
    }

    // heads: lane p computes k = 2*j + p (9 heads each); p==0 also k=18
    if (active) {
        #pragma unroll
        for (int j = 0; j < 9; ++j) {
            int k = 2 * j + p;
            float a0 = bcst[k], a1 = 0.f;
            #pragma unroll
            for (int d = 0; d < D; d += 2) {
                a0 = fmaf(z[d],     Wcst[k * D + d],     a0);
                a1 = fmaf(z[d + 1], Wcst[k * D + d + 1], a1);
            }
            souts[rl * 19 + k] = a0 + a1;
        }
        if (p == 0) {
            float a0 = bcl[0], a1 = 0.f;
            #pragma unroll
            for (int d = 0; d < D; d += 2) {
                a0 = fmaf(z[d],     Wcl[d],     a0);
                a1 = fmaf(z[d + 1], Wcl[d + 1], a1);
            }
            souts[rl * 19 + 18] = a0 + a1;
        }
    }

    __syncthreads();

    // coalesced writeback of this block's 128x19 outputs
    const int base = blockIdx.x * 128;
    int nrows = B - base;
    if (nrows > 128) nrows = 128;
    if (nrows > 0) {
        const int cnt = nrows * 19;
        for (int i = tid; i < cnt; i += 256)
            out[(size_t)base * 19 + i] = souts[i];
    }
}

extern "C" void kernel_launch(void* const* d_in, const int* in_sizes, int n_in,
                              void* d_out, int out_size, void* d_ws, size_t ws_size,
                              hipStream_t stream) {
    const float* cl     = (const float*)d_in[0];
    const float* cd     = (const float*)d_in[1];
    const float* re_log = (const float*)d_in[2];
    const float* mach   = (const float*)d_in[3];
    const float* alpha  = (const float*)d_in[4];
    const float* u      = (const float*)d_in[5];
    const float* We     = (const float*)d_in[6];
    const float* be     = (const float*)d_in[7];
    const float* Bmat   = (const float*)d_in[8];
    const float* Wproj  = (const float*)d_in[9];
    const float* bproj  = (const float*)d_in[10];
    const float* Wr1    = (const float*)d_in[11];
    const float* br1    = (const float*)d_in[12];
    const float* Wr2    = (const float*)d_in[13];
    const float* br2    = (const float*)d_in[14];
    const float* ln_g   = (const float*)d_in[15];
    const float* ln_b   = (const float*)d_in[16];
    const float* Wout   = (const float*)d_in[17];
    const float* bout   = (const float*)d_in[18];
    const float* fg     = (const float*)d_in[19];
    const float* fb     = (const float*)d_in[20];
    const float* Wcst   = (const float*)d_in[21];
    const float* bcst   = (const float*)d_in[22];
    const float* Wcl    = (const float*)d_in[23];
    const float* bcl    = (const float*)d_in[24];

    float* Cpre = (float*)d_ws;   // 96 floats (n-paired layout)
    const int B = in_sizes[0];

    hipLaunchKernelGGL(precompute_C_kernel, dim3(1), dim3(128), 0, stream,
                       Bmat, Wproj, bproj, Cpre);

    const int blocks = (B + 127) / 128;   // 128 rows per 256-thread block
    hipLaunchKernelGGL(whisp_kernel, dim3(blocks), dim3(256), 0, stream,
                       cl, cd, re_log, mach, alpha, u, We, be, Wproj,
                       Wr1, br1, Wr2, br2, ln_g, ln_b, Wout, bout, fg, fb,
                       Wcst, bcst, Wcl, bcl, Cpre, (float*)d_out, B);
}

// Round 18
// 63.533 us; speedup vs baseline: 1.1671x; 1.1671x over previous
//
#include <hip/hip_runtime.h>

#define D 8
#define NE 4
#define NS 3
#define NI 5
#define LN_EPS 1e-5f

// wlds layout: per-stage blocks of 144 floats (576B, 16B-aligned):
//   +0   W1 (64, [d][k])  +64 W2T (32, [d][e])  +96 C (32, n-paired)
//   +128 B1 (8)  +136 B2 (4)  +140 pad(4)
// then Wproj (NS*512) at 432, LN (16) at 1968.
#define STAGE_STRIDE 144
#define SOFF_W1  0
#define SOFF_W2T 64
#define SOFF_C   96
#define SOFF_B1  128
#define SOFF_B2  136
#define OFF_WP   432
#define OFF_LN   1968
#define WLDS_SIZE 1984

typedef float f2 __attribute__((ext_vector_type(2)));

__device__ __forceinline__ f2 fma2(f2 a, f2 b, f2 c) { return __builtin_elementwise_fma(a, b, c); }
__device__ __forceinline__ f2 max2(f2 a, f2 b) { return __builtin_elementwise_max(a, b); }
__device__ __forceinline__ f2 bc(float s) { return (f2){s, s}; }

// ---------------------------------------------------------------------------
// Setup kernel: C in n-PAIRED layout: C[s*32 + ((n>>1)*8 + d)*2 + (n&1)]
// ---------------------------------------------------------------------------
__global__ void precompute_C_kernel(const float* __restrict__ Bmat,
                                    const float* __restrict__ Wproj,
                                    const float* __restrict__ bproj,
                                    float* __restrict__ C) {
    int idx = threadIdx.x;
    if (idx >= NS * NE * D) return;
    int s = idx / (NE * D);
    int rem = idx % (NE * D);
    int n = rem / D;
    int d = rem % D;
    const float* bm = Bmat + ((size_t)s * NE + n) * 64;
    const float* wp = Wproj + ((size_t)s * D + d) * 64;
    float acc = bproj[s * D + d];
    #pragma unroll
    for (int k = 0; k < 64; ++k) acc += bm[k] * wp[k];
    C[s * 32 + ((n >> 1) * 8 + d) * 2 + (n & 1)] = acc;
}

__device__ __forceinline__ float fast_tanh(float x) {
    float e = __expf(2.f * x);
    return 1.f - 2.f * __builtin_amdgcn_rcpf(e + 1.f);
}

__device__ __forceinline__ float4 ld4(const float* p) {
    return *reinterpret_cast<const float4*>(p);
}

// ---------------------------------------------------------------------------
// Main kernel: R15 structure EXACTLY (1 thread/row, f2 n-packing, t[8][8] in
// regs f32, per-stage LDS blocks, one gated pointer/iter, no spill) with ONE
// change: the NI loop is FULLY UNROLLED. Rationale (R16/R17 post-mortems):
// v_pk_fma_f32 is not dual-rate on CDNA4 (fp32 peak 157.3 TF = scalar rate),
// so R15's ~33us busy is the issue floor; the 27us idle is LDS latency that
// 2 phase-locked waves/SIMD can't hide (3 lane-split attempts all regressed).
// Unrolling lets the scheduler hoist iteration i+1's broadcast ds_reads
// (address depends only on the per-iteration opaque-zero gate, no memory
// clobber) above iteration i's softmax tail -> cross-iteration pipelining
// within one wave. The per-iteration gate stays: it bounds LICM so the ~112
// invariant weight floats never become simultaneously live.
// Tripwire: WRITE_SIZE must stay 9728 KB (no spill).
// ---------------------------------------------------------------------------
__global__ __launch_bounds__(256, 2) void whisp_kernel(
    const float* __restrict__ cl, const float* __restrict__ cd,
    const float* __restrict__ re_log, const float* __restrict__ mach,
    const float* __restrict__ alpha, const float* __restrict__ u,
    const float* __restrict__ We, const float* __restrict__ be,
    const float* __restrict__ Wproj,
    const float* __restrict__ Wr1, const float* __restrict__ br1,
    const float* __restrict__ Wr2, const float* __restrict__ br2,
    const float* __restrict__ ln_g, const float* __restrict__ ln_b,
    const float* __restrict__ Wout, const float* __restrict__ bout,
    const float* __restrict__ fg, const float* __restrict__ fb,
    const float* __restrict__ Wcst, const float* __restrict__ bcst,
    const float* __restrict__ Wcl, const float* __restrict__ bcl,
    const float* __restrict__ Cpre,
    float* __restrict__ out, int B)
{
    __shared__ __align__(16) float wlds[WLDS_SIZE];   // 7936 B
    __shared__ __align__(16) float4 ubuf[2 * 256];    // 8192 B (per-thread uu)
    __shared__ float souts[256 * 19];                 // 19456 B

    const int tid = threadIdx.x;
    const int row0 = blockIdx.x * 256 + tid;
    const bool active = (row0 < B);
    const int row = active ? row0 : (B - 1);

    // ---- stage hot-loop weights into per-stage LDS blocks ----
    for (int i = tid; i < NS * 64; i += 256) {         // W1 natural
        int s = i / 64, j = i % 64;
        wlds[s * STAGE_STRIDE + SOFF_W1 + j] = Wr1[i];
    }
    for (int i = tid; i < NS * 32; i += 256) {         // W2 -> [d][e]
        int s = i / 32, j = i % 32, d = j / 4, e = j % 4;
        wlds[s * STAGE_STRIDE + SOFF_W2T + j] = Wr2[s * 32 + e * 8 + d];
    }
    for (int i = tid; i < NS * 32; i += 256) {         // C (already n-paired)
        int s = i / 32, j = i % 32;
        wlds[s * STAGE_STRIDE + SOFF_C + j] = Cpre[i];
    }
    for (int i = tid; i < NS * 8; i += 256) {          // B1
        int s = i / 8, j = i % 8;
        wlds[s * STAGE_STRIDE + SOFF_B1 + j] = br1[i];
    }
    for (int i = tid; i < NS * 4; i += 256) {          // B2
        int s = i / 4, j = i % 4;
        wlds[s * STAGE_STRIDE + SOFF_B2 + j] = br2[i];
    }
    for (int i = tid; i < 1536; i += 256) wlds[OFF_WP + i] = Wproj[i];
    for (int i = tid; i < 8; i += 256) { wlds[OFF_LN + i] = ln_g[i]; wlds[OFF_LN + 8 + i] = ln_b[i]; }

    // ---- per-row inputs; uu stashed in per-thread LDS (frees 8 regs) ----
    {
        const float4* up = reinterpret_cast<const float4*>(u + (size_t)row * D);
        ubuf[tid]       = up[0];
        ubuf[256 + tid] = up[1];
    }
    float xs[NE] = { cl[row], cd[row], re_log[row], mach[row] };
    float al = alpha[row];

    // ---- embedding -> E2[nn][d] = (E[2nn][d], E[2nn+1][d]) ----
    f2 E2[2][D];
    #pragma unroll
    for (int nn = 0; nn < 2; ++nn) {
        #pragma unroll
        for (int d = 0; d < D; ++d) {
            int na = 2 * nn, nb = 2 * nn + 1;
            float pa = We[na * 16 + d * 2] * xs[na] + We[na * 16 + d * 2 + 1] * al + be[na * D + d];
            float pb = We[nb * 16 + d * 2] * xs[nb] + We[nb * 16 + d * 2 + 1] * al + be[nb * D + d];
            E2[nn][d] = (f2){ fast_tanh(pa), fast_tanh(pb) };
        }
    }

    __syncthreads();   // wlds + ubuf ready

    int zero = 0;      // opaque 0: blocks LICM of broadcast weight loads

    // ---- outer stages ----
    #pragma unroll 1
    for (int s = 0; s < NS; ++s) {
        const float* stage_base = wlds + s * STAGE_STRIDE;

        // t[d][i] = sum_j u[j]*Wp[d][i*8+j] -> REGISTERS (f32, exact).
        float t[D][D];
        {
            float4 uq0 = ubuf[tid], uq1 = ubuf[256 + tid];
            f2 uu2[4] = { {uq0.x,uq0.y}, {uq0.z,uq0.w}, {uq1.x,uq1.y}, {uq1.z,uq1.w} };
            const float* Wp = wlds + OFF_WP + s * 512;
            #pragma unroll
            for (int d = 0; d < D; ++d) {
                #pragma unroll
                for (int i = 0; i < D; ++i) {
                    float4 wa = ld4(Wp + d * 64 + i * 8);
                    float4 wb = ld4(Wp + d * 64 + i * 8 + 4);
                    f2 acc = uu2[0] * (f2){wa.x, wa.y};
                    acc = fma2(uu2[1], (f2){wa.z, wa.w}, acc);
                    acc = fma2(uu2[2], (f2){wb.x, wb.y}, acc);
                    acc = fma2(uu2[3], (f2){wb.z, wb.w}, acc);
                    t[d][i] = acc.x + acc.y;
                }
            }
        }

        #pragma unroll            // FULL UNROLL: cross-iteration pipelining
        for (int it = 0; it < NI; ++it) {
            // ONE gated base; all weight reads are imm offsets off it
            asm volatile("" : "+v"(zero));
            const float* sb = stage_base + zero;

            // H init from n-paired C (broadcast, imm offsets)
            f2 H2[2][D];
            #pragma unroll
            for (int nn = 0; nn < 2; ++nn) {
                #pragma unroll
                for (int dp = 0; dp < 4; ++dp) {
                    float4 cq = ld4(sb + SOFF_C + nn * 16 + dp * 4);
                    H2[nn][2 * dp]     = (f2){cq.x, cq.y};
                    H2[nn][2 * dp + 1] = (f2){cq.z, cq.w};
                }
            }
            // H2[nn][d] += sum_i E2[nn][i] * t[d][i]  (t from registers)
            #pragma unroll
            for (int d = 0; d < D; ++d) {
                #pragma unroll
                for (int nn = 0; nn < 2; ++nn) {
                    f2 acc = H2[nn][d];
                    acc = fma2(E2[nn][0], bc(t[d][0]), acc);
                    acc = fma2(E2[nn][1], bc(t[d][1]), acc);
                    acc = fma2(E2[nn][2], bc(t[d][2]), acc);
                    acc = fma2(E2[nn][3], bc(t[d][3]), acc);
                    acc = fma2(E2[nn][4], bc(t[d][4]), acc);
                    acc = fma2(E2[nn][5], bc(t[d][5]), acc);
                    acc = fma2(E2[nn][6], bc(t[d][6]), acc);
                    acc = fma2(E2[nn][7], bc(t[d][7]), acc);
                    H2[nn][d] = acc;
                }
            }

            // lg init from B2 (4 transient scalar broadcasts)
            f2 lg2[2][NE];
            {
                float b20 = sb[SOFF_B2 + 0], b21 = sb[SOFF_B2 + 1];
                float b22 = sb[SOFF_B2 + 2], b23 = sb[SOFF_B2 + 3];
                #pragma unroll
                for (int nn = 0; nn < 2; ++nn) {
                    lg2[nn][0] = bc(b20); lg2[nn][1] = bc(b21);
                    lg2[nn][2] = bc(b22); lg2[nn][3] = bc(b23);
                }
            }

            // fused routing: per d compute r2 then accumulate into lg
            #pragma unroll
            for (int d = 0; d < D; ++d) {
                float4 wa = ld4(sb + SOFF_W1 + d * 8);
                float4 wb = ld4(sb + SOFF_W1 + d * 8 + 4);
                float4 w2 = ld4(sb + SOFF_W2T + d * 4);
                float b1d = sb[SOFF_B1 + d];          // per-d scalar broadcast
                #pragma unroll
                for (int nn = 0; nn < 2; ++nn) {
                    f2 acc = bc(b1d);
                    acc = fma2(H2[nn][0], bc(wa.x), acc);
                    acc = fma2(H2[nn][1], bc(wa.y), acc);
                    acc = fma2(H2[nn][2], bc(wa.z), acc);
                    acc = fma2(H2[nn][3], bc(wa.w), acc);
                    acc = fma2(H2[nn][4], bc(wb.x), acc);
                    acc = fma2(H2[nn][5], bc(wb.y), acc);
                    acc = fma2(H2[nn][6], bc(wb.z), acc);
                    acc = fma2(H2[nn][7], bc(wb.w), acc);
                    f2 r2 = max2(acc, bc(0.f));
                    lg2[nn][0] = fma2(r2, bc(w2.x), lg2[nn][0]);
                    lg2[nn][1] = fma2(r2, bc(w2.y), lg2[nn][1]);
                    lg2[nn][2] = fma2(r2, bc(w2.z), lg2[nn][2]);
                    lg2[nn][3] = fma2(r2, bc(w2.w), lg2[nn][3]);
                }
            }

            // packed softmax over e (per n; n's in f2 lanes)
            f2 sm2[2][NE];
            #pragma unroll
            for (int nn = 0; nn < 2; ++nn) {
                f2 m2 = max2(max2(lg2[nn][0], lg2[nn][1]), max2(lg2[nn][2], lg2[nn][3]));
                f2 ee[NE];
                #pragma unroll
                for (int e = 0; e < NE; ++e) {
                    f2 tt = lg2[nn][e] - m2;
                    ee[e] = (f2){ __expf(tt.x), __expf(tt.y) };
                }
                f2 s2 = (ee[0] + ee[1]) + (ee[2] + ee[3]);
                f2 inv2 = (f2){ __builtin_amdgcn_rcpf(s2.x), __builtin_amdgcn_rcpf(s2.y) };
                #pragma unroll
                for (int e = 0; e < NE; ++e) sm2[nn][e] = ee[e] * inv2;
            }

            // E2[nn][d] += sum_e sm2[nn][e] * H[e][d]
            #pragma unroll
            for (int d = 0; d < D; ++d) {
                #pragma unroll
                for (int nn = 0; nn < 2; ++nn) {
                    f2 acc = E2[nn][d];
                    acc = fma2(sm2[nn][0], bc(H2[0][d].x), acc);
                    acc = fma2(sm2[nn][1], bc(H2[0][d].y), acc);
                    acc = fma2(sm2[nn][2], bc(H2[1][d].x), acc);
                    acc = fma2(sm2[nn][3], bc(H2[1][d].y), acc);
                    E2[nn][d] = acc;
                }
            }
        }

        // post-stage LayerNorm (params from LDS; packed math)
        float lngv[8], lnbv[8];
        {
            float4 g0 = ld4(wlds + OFF_LN),     g1 = ld4(wlds + OFF_LN + 4);
            float4 b0 = ld4(wlds + OFF_LN + 8), b1 = ld4(wlds + OFF_LN + 12);
            lngv[0]=g0.x; lngv[1]=g0.y; lngv[2]=g0.z; lngv[3]=g0.w;
            lngv[4]=g1.x; lngv[5]=g1.y; lngv[6]=g1.z; lngv[7]=g1.w;
            lnbv[0]=b0.x; lnbv[1]=b0.y; lnbv[2]=b0.z; lnbv[3]=b0.w;
            lnbv[4]=b1.x; lnbv[5]=b1.y; lnbv[6]=b1.z; lnbv[7]=b1.w;
        }
        #pragma unroll
        for (int nn = 0; nn < 2; ++nn) {
            f2 s2 = (E2[nn][0] + E2[nn][1]) + (E2[nn][2] + E2[nn][3]);
            s2 = s2 + (E2[nn][4] + E2[nn][5]) + (E2[nn][6] + E2[nn][7]);
            f2 m2 = s2 * bc(0.125f);
            f2 v2 = bc(0.f);
            #pragma unroll
            for (int d = 0; d < D; ++d) { f2 c = E2[nn][d] - m2; v2 = fma2(c, c, v2); }
            v2 = v2 * bc(0.125f);
            f2 inv2 = (f2){ __builtin_amdgcn_rsqf(v2.x + LN_EPS),
                            __builtin_amdgcn_rsqf(v2.y + LN_EPS) };
            #pragma unroll
            for (int d = 0; d < D; ++d)
                E2[nn][d] = fma2((E2[nn][d] - m2) * inv2, bc(lngv[d]), bc(lnbv[d]));
        }
    }

    // ---- final mixing (one-time global weights; scalar epilogue) ----
    float lgf[NE];
    #pragma unroll
    for (int e = 0; e < NE; ++e) {
        float a0 = bout[e], a1 = 0.f;
        #pragma unroll
        for (int d = 0; d < D; ++d) {
            a0 = fmaf(E2[0][d].x, Wout[e * 32 + 0 * D + d], a0);
            a1 = fmaf(E2[0][d].y, Wout[e * 32 + 1 * D + d], a1);
            a0 = fmaf(E2[1][d].x, Wout[e * 32 + 2 * D + d], a0);
            a1 = fmaf(E2[1][d].y, Wout[e * 32 + 3 * D + d], a1);
        }
        lgf[e] = a0 + a1;
    }
    float mx = fmaxf(fmaxf(lgf[0], lgf[1]), fmaxf(lgf[2], lgf[3]));
    float w0 = __expf(lgf[0] - mx), w1 = __expf(lgf[1] - mx);
    float w2 = __expf(lgf[2] - mx), w3 = __expf(lgf[3] - mx);
    float winv = __builtin_amdgcn_rcpf((w0 + w1) + (w2 + w3));
    w0 *= winv; w1 *= winv; w2 *= winv; w3 *= winv;

    float z[D];
    #pragma unroll
    for (int d = 0; d < D; ++d) {
        float a0 = w0 * E2[0][d].x;
        float a1 = w1 * E2[0][d].y;
        a0 = fmaf(w2, E2[1][d].x, a0);
        a1 = fmaf(w3, E2[1][d].y, a1);
        z[d] = a0 + a1;
    }
    float zm = 0.f;
    #pragma unroll
    for (int d = 0; d < D; ++d) zm += z[d];
    zm *= (1.f / D);
    float zv = 0.f;
    #pragma unroll
    for (int d = 0; d < D; ++d) { float c = z[d] - zm; zv = fmaf(c, c, zv); }
    zv *= (1.f / D);
    float zinv = __builtin_amdgcn_rsqf(zv + LN_EPS);
    #pragma unroll
    for (int d = 0; d < D; ++d)
        z[d] = (z[d] - zm) * zinv * fg[d] + fb[d];

    // heads
    float zout[19];
    #pragma unroll
    for (int k = 0; k < 18; ++k) {
        float a0 = bcst[k], a1 = 0.f;
        #pragma unroll
        for (int d = 0; d < D; d += 2) {
            a0 = fmaf(z[d],     Wcst[k * D + d],     a0);
            a1 = fmaf(z[d + 1], Wcst[k * D + d + 1], a1);
        }
        zout[k] = a0 + a1;
    }
    {
        float a0 = bcl[0], a1 = 0.f;
        #pragma unroll
        for (int d = 0; d < D; d += 2) {
            a0 = fmaf(z[d],     Wcl[d],     a0);
            a1 = fmaf(z[d + 1], Wcl[d + 1], a1);
        }
        zout[18] = a0 + a1;
    }

    // stage via LDS for coalesced stores
    if (active) {
        #pragma unroll
        for (int k = 0; k < 19; ++k) souts[tid * 19 + k] = zout[k];
    }
    __syncthreads();

    const int base = blockIdx.x * 256;
    int nrows = B - base;
    if (nrows > 256) nrows = 256;
    if (nrows > 0) {
        const int cnt = nrows * 19;
        for (int i = tid; i < cnt; i += 256)
            out[(size_t)base * 19 + i] = souts[i];
    }
}

extern "C" void kernel_launch(void* const* d_in, const int* in_sizes, int n_in,
                              void* d_out, int out_size, void* d_ws, size_t ws_size,
                              hipStream_t stream) {
    const float* cl     = (const float*)d_in[0];
    const float* cd     = (const float*)d_in[1];
    const float* re_log = (const float*)d_in[2];
    const float* mach   = (const float*)d_in[3];
    const float* alpha  = (const float*)d_in[4];
    const float* u      = (const float*)d_in[5];
    const float* We     = (const float*)d_in[6];
    const float* be     = (const float*)d_in[7];
    const float* Bmat   = (const float*)d_in[8];
    const float* Wproj  = (const float*)d_in[9];
    const float* bproj  = (const float*)d_in[10];
    const float* Wr1    = (const float*)d_in[11];
    const float* br1    = (const float*)d_in[12];
    const float* Wr2    = (const float*)d_in[13];
    const float* br2    = (const float*)d_in[14];
    const float* ln_g   = (const float*)d_in[15];
    const float* ln_b   = (const float*)d_in[16];
    const float* Wout   = (const float*)d_in[17];
    const float* bout   = (const float*)d_in[18];
    const float* fg     = (const float*)d_in[19];
    const float* fb     = (const float*)d_in[20];
    const float* Wcst   = (const float*)d_in[21];
    const float* bcst   = (const float*)d_in[22];
    const float* Wcl    = (const float*)d_in[23];
    const float* bcl    = (const float*)d_in[24];

    float* Cpre = (float*)d_ws;   // 96 floats (n-paired layout)
    const int B = in_sizes[0];

    hipLaunchKernelGGL(precompute_C_kernel, dim3(1), dim3(128), 0, stream,
                       Bmat, Wproj, bproj, Cpre);

    const int blocks = (B + 255) / 256;
    hipLaunchKernelGGL(whisp_kernel, dim3(blocks), dim3(256), 0, stream,
                       cl, cd, re_log, mach, alpha, u, We, be, Wproj,
                       Wr1, br1, Wr2, br2, ln_g, ln_b, Wout, bout, fg, fb,
                       Wcst, bcst, Wcl, bcl, Cpre, (float*)d_out, B);
}

// Round 19
// 60.198 us; speedup vs baseline: 1.2318x; 1.0554x over previous
//
#include <hip/hip_runtime.h>

#define D 8
#define NE 4
#define NS 3
#define NI 5
#define LN_EPS 1e-5f

// wlds layout: per-stage blocks of 144 floats (576B, 16B-aligned):
//   +0   W1 (64, [d][k])  +64 W2T (32, [d][e])  +96 C (32, n-paired)
//   +128 B1 (8)  +136 B2 (4)  +140 pad(4)
// then Wproj (NS*512) at 432, LN (16) at 1968.
#define STAGE_STRIDE 144
#define SOFF_W1  0
#define SOFF_W2T 64
#define SOFF_C   96
#define SOFF_B1  128
#define SOFF_B2  136
#define OFF_WP   432
#define OFF_LN   1968
#define WLDS_SIZE 1984

typedef float f2 __attribute__((ext_vector_type(2)));

__device__ __forceinline__ f2 fma2(f2 a, f2 b, f2 c) { return __builtin_elementwise_fma(a, b, c); }
__device__ __forceinline__ f2 max2(f2 a, f2 b) { return __builtin_elementwise_max(a, b); }
__device__ __forceinline__ f2 bc(float s) { return (f2){s, s}; }

// ---------------------------------------------------------------------------
// Setup kernel: C in n-PAIRED layout: C[s*32 + ((n>>1)*8 + d)*2 + (n&1)]
// ---------------------------------------------------------------------------
__global__ void precompute_C_kernel(const float* __restrict__ Bmat,
                                    const float* __restrict__ Wproj,
                                    const float* __restrict__ bproj,
                                    float* __restrict__ C) {
    int idx = threadIdx.x;
    if (idx >= NS * NE * D) return;
    int s = idx / (NE * D);
    int rem = idx % (NE * D);
    int n = rem / D;
    int d = rem % D;
    const float* bm = Bmat + ((size_t)s * NE + n) * 64;
    const float* wp = Wproj + ((size_t)s * D + d) * 64;
    float acc = bproj[s * D + d];
    #pragma unroll
    for (int k = 0; k < 64; ++k) acc += bm[k] * wp[k];
    C[s * 32 + ((n >> 1) * 8 + d) * 2 + (n & 1)] = acc;
}

__device__ __forceinline__ float fast_tanh(float x) {
    float e = __expf(2.f * x);
    return 1.f - 2.f * __builtin_amdgcn_rcpf(e + 1.f);
}

__device__ __forceinline__ float4 ld4(const float* p) {
    return *reinterpret_cast<const float4*>(p);
}

// ---------------------------------------------------------------------------
// Main kernel: R15 structure EXACTLY (session best, 60.6us: 1 thread/row, f2
// n-packing, t[8][8] in regs f32, per-stage LDS blocks, ONE gated pointer per
// iteration, rolled NI loop, no spill) + R19: WAVE DE-PHASING.
// Rationale: 2 waves/SIMD (grid-capped) run byte-identical code launched
// simultaneously -> phase-locked; their dependent-ds_read/exp stalls coincide
// so neither hides the other's latency (VALUBusy pinned ~55% across
// R9-R15). Odd waves (XCD-aware parity) sleep ~256cyc (half an iteration
// rhythm) after the staging barrier -> anti-phase -> one wave's stall window
// lands under the other's compute. Zero register/correctness cost.
// (R18 post-mortem: full unroll null — volatile gates are mutually ordered
// and 5x body breaks 32KB L1I. Rolled loop restored.)
// ---------------------------------------------------------------------------
__global__ __launch_bounds__(256, 2) void whisp_kernel(
    const float* __restrict__ cl, const float* __restrict__ cd,
    const float* __restrict__ re_log, const float* __restrict__ mach,
    const float* __restrict__ alpha, const float* __restrict__ u,
    const float* __restrict__ We, const float* __restrict__ be,
    const float* __restrict__ Wproj,
    const float* __restrict__ Wr1, const float* __restrict__ br1,
    const float* __restrict__ Wr2, const float* __restrict__ br2,
    const float* __restrict__ ln_g, const float* __restrict__ ln_b,
    const float* __restrict__ Wout, const float* __restrict__ bout,
    const float* __restrict__ fg, const float* __restrict__ fb,
    const float* __restrict__ Wcst, const float* __restrict__ bcst,
    const float* __restrict__ Wcl, const float* __restrict__ bcl,
    const float* __restrict__ Cpre,
    float* __restrict__ out, int B)
{
    __shared__ __align__(16) float wlds[WLDS_SIZE];   // 7936 B
    __shared__ __align__(16) float4 ubuf[2 * 256];    // 8192 B (per-thread uu)
    __shared__ float souts[256 * 19];                 // 19456 B

    const int tid = threadIdx.x;
    const int row0 = blockIdx.x * 256 + tid;
    const bool active = (row0 < B);
    const int row = active ? row0 : (B - 1);

    // ---- stage hot-loop weights into per-stage LDS blocks ----
    for (int i = tid; i < NS * 64; i += 256) {         // W1 natural
        int s = i / 64, j = i % 64;
        wlds[s * STAGE_STRIDE + SOFF_W1 + j] = Wr1[i];
    }
    for (int i = tid; i < NS * 32; i += 256) {         // W2 -> [d][e]
        int s = i / 32, j = i % 32, d = j / 4, e = j % 4;
        wlds[s * STAGE_STRIDE + SOFF_W2T + j] = Wr2[s * 32 + e * 8 + d];
    }
    for (int i = tid; i < NS * 32; i += 256) {         // C (already n-paired)
        int s = i / 32, j = i % 32;
        wlds[s * STAGE_STRIDE + SOFF_C + j] = Cpre[i];
    }
    for (int i = tid; i < NS * 8; i += 256) {          // B1
        int s = i / 8, j = i % 8;
        wlds[s * STAGE_STRIDE + SOFF_B1 + j] = br1[i];
    }
    for (int i = tid; i < NS * 4; i += 256) {          // B2
        int s = i / 4, j = i % 4;
        wlds[s * STAGE_STRIDE + SOFF_B2 + j] = br2[i];
    }
    for (int i = tid; i < 1536; i += 256) wlds[OFF_WP + i] = Wproj[i];
    for (int i = tid; i < 8; i += 256) { wlds[OFF_LN + i] = ln_g[i]; wlds[OFF_LN + 8 + i] = ln_b[i]; }

    // ---- per-row inputs; uu stashed in per-thread LDS (frees 8 regs) ----
    {
        const float4* up = reinterpret_cast<const float4*>(u + (size_t)row * D);
        ubuf[tid]       = up[0];
        ubuf[256 + tid] = up[1];
    }
    float xs[NE] = { cl[row], cd[row], re_log[row], mach[row] };
    float al = alpha[row];

    // ---- embedding -> E2[nn][d] = (E[2nn][d], E[2nn+1][d]) ----
    f2 E2[2][D];
    #pragma unroll
    for (int nn = 0; nn < 2; ++nn) {
        #pragma unroll
        for (int d = 0; d < D; ++d) {
            int na = 2 * nn, nb = 2 * nn + 1;
            float pa = We[na * 16 + d * 2] * xs[na] + We[na * 16 + d * 2 + 1] * al + be[na * D + d];
            float pb = We[nb * 16 + d * 2] * xs[nb] + We[nb * 16 + d * 2 + 1] * al + be[nb * D + d];
            E2[nn][d] = (f2){ fast_tanh(pa), fast_tanh(pb) };
        }
    }

    __syncthreads();   // wlds + ubuf ready

    // ---- de-phase co-resident waves (anti-phase stall/compute rhythm) ----
    if (((blockIdx.x >> 3) ^ (tid >> 6)) & 1)
        __builtin_amdgcn_s_sleep(4);   // ~256 cyc ~= half an iteration period

    int zero = 0;      // opaque 0: blocks LICM of broadcast weight loads

    // ---- outer stages ----
    #pragma unroll 1
    for (int s = 0; s < NS; ++s) {
        const float* stage_base = wlds + s * STAGE_STRIDE;

        // t[d][i] = sum_j u[j]*Wp[d][i*8+j] -> REGISTERS (f32, exact).
        float t[D][D];
        {
            float4 uq0 = ubuf[tid], uq1 = ubuf[256 + tid];
            f2 uu2[4] = { {uq0.x,uq0.y}, {uq0.z,uq0.w}, {uq1.x,uq1.y}, {uq1.z,uq1.w} };
            const float* Wp = wlds + OFF_WP + s * 512;
            #pragma unroll
            for (int d = 0; d < D; ++d) {
                #pragma unroll
                for (int i = 0; i < D; ++i) {
                    float4 wa = ld4(Wp + d * 64 + i * 8);
                    float4 wb = ld4(Wp + d * 64 + i * 8 + 4);
                    f2 acc = uu2[0] * (f2){wa.x, wa.y};
                    acc = fma2(uu2[1], (f2){wa.z, wa.w}, acc);
                    acc = fma2(uu2[2], (f2){wb.x, wb.y}, acc);
                    acc = fma2(uu2[3], (f2){wb.z, wb.w}, acc);
                    t[d][i] = acc.x + acc.y;
                }
            }
        }

        #pragma unroll 1
        for (int it = 0; it < NI; ++it) {
            // ONE gated base; all weight reads are imm offsets off it
            asm volatile("" : "+v"(zero));
            const float* sb = stage_base + zero;

            // H init from n-paired C (broadcast, imm offsets)
            f2 H2[2][D];
            #pragma unroll
            for (int nn = 0; nn < 2; ++nn) {
                #pragma unroll
                for (int dp = 0; dp < 4; ++dp) {
                    float4 cq = ld4(sb + SOFF_C + nn * 16 + dp * 4);
                    H2[nn][2 * dp]     = (f2){cq.x, cq.y};
                    H2[nn][2 * dp + 1] = (f2){cq.z, cq.w};
                }
            }
            // H2[nn][d] += sum_i E2[nn][i] * t[d][i]  (t from registers)
            #pragma unroll
            for (int d = 0; d < D; ++d) {
                #pragma unroll
                for (int nn = 0; nn < 2; ++nn) {
                    f2 acc = H2[nn][d];
                    acc = fma2(E2[nn][0], bc(t[d][0]), acc);
                    acc = fma2(E2[nn][1], bc(t[d][1]), acc);
                    acc = fma2(E2[nn][2], bc(t[d][2]), acc);
                    acc = fma2(E2[nn][3], bc(t[d][3]), acc);
                    acc = fma2(E2[nn][4], bc(t[d][4]), acc);
                    acc = fma2(E2[nn][5], bc(t[d][5]), acc);
                    acc = fma2(E2[nn][6], bc(t[d][6]), acc);
                    acc = fma2(E2[nn][7], bc(t[d][7]), acc);
                    H2[nn][d] = acc;
                }
            }

            // lg init from B2 (4 transient scalar broadcasts)
            f2 lg2[2][NE];
            {
                float b20 = sb[SOFF_B2 + 0], b21 = sb[SOFF_B2 + 1];
                float b22 = sb[SOFF_B2 + 2], b23 = sb[SOFF_B2 + 3];
                #pragma unroll
                for (int nn = 0; nn < 2; ++nn) {
                    lg2[nn][0] = bc(b20); lg2[nn][1] = bc(b21);
                    lg2[nn][2] = bc(b22); lg2[nn][3] = bc(b23);
                }
            }

            // fused routing: per d compute r2 then accumulate into lg
            #pragma unroll
            for (int d = 0; d < D; ++d) {
                float4 wa = ld4(sb + SOFF_W1 + d * 8);
                float4 wb = ld4(sb + SOFF_W1 + d * 8 + 4);
                float4 w2 = ld4(sb + SOFF_W2T + d * 4);
                float b1d = sb[SOFF_B1 + d];          // per-d scalar broadcast
                #pragma unroll
                for (int nn = 0; nn < 2; ++nn) {
                    f2 acc = bc(b1d);
                    acc = fma2(H2[nn][0], bc(wa.x), acc);
                    acc = fma2(H2[nn][1], bc(wa.y), acc);
                    acc = fma2(H2[nn][2], bc(wa.z), acc);
                    acc = fma2(H2[nn][3], bc(wa.w), acc);
                    acc = fma2(H2[nn][4], bc(wb.x), acc);
                    acc = fma2(H2[nn][5], bc(wb.y), acc);
                    acc = fma2(H2[nn][6], bc(wb.z), acc);
                    acc = fma2(H2[nn][7], bc(wb.w), acc);
                    f2 r2 = max2(acc, bc(0.f));
                    lg2[nn][0] = fma2(r2, bc(w2.x), lg2[nn][0]);
                    lg2[nn][1] = fma2(r2, bc(w2.y), lg2[nn][1]);
                    lg2[nn][2] = fma2(r2, bc(w2.z), lg2[nn][2]);
                    lg2[nn][3] = fma2(r2, bc(w2.w), lg2[nn][3]);
                }
            }

            // packed softmax over e (per n; n's in f2 lanes)
            f2 sm2[2][NE];
            #pragma unroll
            for (int nn = 0; nn < 2; ++nn) {
                f2 m2 = max2(max2(lg2[nn][0], lg2[nn][1]), max2(lg2[nn][2], lg2[nn][3]));
                f2 ee[NE];
                #pragma unroll
                for (int e = 0; e < NE; ++e) {
                    f2 tt = lg2[nn][e] - m2;
                    ee[e] = (f2){ __expf(tt.x), __expf(tt.y) };
                }
                f2 s2 = (ee[0] + ee[1]) + (ee[2] + ee[3]);
                f2 inv2 = (f2){ __builtin_amdgcn_rcpf(s2.x), __builtin_amdgcn_rcpf(s2.y) };
                #pragma unroll
                for (int e = 0; e < NE; ++e) sm2[nn][e] = ee[e] * inv2;
            }

            // E2[nn][d] += sum_e sm2[nn][e] * H[e][d]
            #pragma unroll
            for (int d = 0; d < D; ++d) {
                #pragma unroll
                for (int nn = 0; nn < 2; ++nn) {
                    f2 acc = E2[nn][d];
                    acc = fma2(sm2[nn][0], bc(H2[0][d].x), acc);
                    acc = fma2(sm2[nn][1], bc(H2[0][d].y), acc);
                    acc = fma2(sm2[nn][2], bc(H2[1][d].x), acc);
                    acc = fma2(sm2[nn][3], bc(H2[1][d].y), acc);
                    E2[nn][d] = acc;
                }
            }
        }

        // post-stage LayerNorm (params from LDS; packed math)
        float lngv[8], lnbv[8];
        {
            float4 g0 = ld4(wlds + OFF_LN),     g1 = ld4(wlds + OFF_LN + 4);
            float4 b0 = ld4(wlds + OFF_LN + 8), b1 = ld4(wlds + OFF_LN + 12);
            lngv[0]=g0.x; lngv[1]=g0.y; lngv[2]=g0.z; lngv[3]=g0.w;
            lngv[4]=g1.x; lngv[5]=g1.y; lngv[6]=g1.z; lngv[7]=g1.w;
            lnbv[0]=b0.x; lnbv[1]=b0.y; lnbv[2]=b0.z; lnbv[3]=b0.w;
            lnbv[4]=b1.x; lnbv[5]=b1.y; lnbv[6]=b1.z; lnbv[7]=b1.w;
        }
        #pragma unroll
        for (int nn = 0; nn < 2; ++nn) {
            f2 s2 = (E2[nn][0] + E2[nn][1]) + (E2[nn][2] + E2[nn][3]);
            s2 = s2 + (E2[nn][4] + E2[nn][5]) + (E2[nn][6] + E2[nn][7]);
            f2 m2 = s2 * bc(0.125f);
            f2 v2 = bc(0.f);
            #pragma unroll
            for (int d = 0; d < D; ++d) { f2 c = E2[nn][d] - m2; v2 = fma2(c, c, v2); }
            v2 = v2 * bc(0.125f);
            f2 inv2 = (f2){ __builtin_amdgcn_rsqf(v2.x + LN_EPS),
                            __builtin_amdgcn_rsqf(v2.y + LN_EPS) };
            #pragma unroll
            for (int d = 0; d < D; ++d)
                E2[nn][d] = fma2((E2[nn][d] - m2) * inv2, bc(lngv[d]), bc(lnbv[d]));
        }
    }

    // ---- final mixing (one-time global weights; scalar epilogue) ----
    float lgf[NE];
    #pragma unroll
    for (int e = 0; e < NE; ++e) {
        float a0 = bout[e], a1 = 0.f;
        #pragma unroll
        for (int d = 0; d < D; ++d) {
            a0 = fmaf(E2[0][d].x, Wout[e * 32 + 0 * D + d], a0);
            a1 = fmaf(E2[0][d].y, Wout[e * 32 + 1 * D + d], a1);
            a0 = fmaf(E2[1][d].x, Wout[e * 32 + 2 * D + d], a0);
            a1 = fmaf(E2[1][d].y, Wout[e * 32 + 3 * D + d], a1);
        }
        lgf[e] = a0 + a1;
    }
    float mx = fmaxf(fmaxf(lgf[0], lgf[1]), fmaxf(lgf[2], lgf[3]));
    float w0 = __expf(lgf[0] - mx), w1 = __expf(lgf[1] - mx);
    float w2 = __expf(lgf[2] - mx), w3 = __expf(lgf[3] - mx);
    float winv = __builtin_amdgcn_rcpf((w0 + w1) + (w2 + w3));
    w0 *= winv; w1 *= winv; w2 *= winv; w3 *= winv;

    float z[D];
    #pragma unroll
    for (int d = 0; d < D; ++d) {
        float a0 = w0 * E2[0][d].x;
        float a1 = w1 * E2[0][d].y;
        a0 = fmaf(w2, E2[1][d].x, a0);
        a1 = fmaf(w3, E2[1][d].y, a1);
        z[d] = a0 + a1;
    }
    float zm = 0.f;
    #pragma unroll
    for (int d = 0; d < D; ++d) zm += z[d];
    zm *= (1.f / D);
    float zv = 0.f;
    #pragma unroll
    for (int d = 0; d < D; ++d) { float c = z[d] - zm; zv = fmaf(c, c, zv); }
    zv *= (1.f / D);
    float zinv = __builtin_amdgcn_rsqf(zv + LN_EPS);
    #pragma unroll
    for (int d = 0; d < D; ++d)
        z[d] = (z[d] - zm) * zinv * fg[d] + fb[d];

    // heads
    float zout[19];
    #pragma unroll
    for (int k = 0; k < 18; ++k) {
        float a0 = bcst[k], a1 = 0.f;
        #pragma unroll
        for (int d = 0; d < D; d += 2) {
            a0 = fmaf(z[d],     Wcst[k * D + d],     a0);
            a1 = fmaf(z[d + 1], Wcst[k * D + d + 1], a1);
        }
        zout[k] = a0 + a1;
    }
    {
        float a0 = bcl[0], a1 = 0.f;
        #pragma unroll
        for (int d = 0; d < D; d += 2) {
            a0 = fmaf(z[d],     Wcl[d],     a0);
            a1 = fmaf(z[d + 1], Wcl[d + 1], a1);
        }
        zout[18] = a0 + a1;
    }

    // stage via LDS for coalesced stores
    if (active) {
        #pragma unroll
        for (int k = 0; k < 19; ++k) souts[tid * 19 + k] = zout[k];
    }
    __syncthreads();

    const int base = blockIdx.x * 256;
    int nrows = B - base;
    if (nrows > 256) nrows = 256;
    if (nrows > 0) {
        const int cnt = nrows * 19;
        for (int i = tid; i < cnt; i += 256)
            out[(size_t)base * 19 + i] = souts[i];
    }
}

extern "C" void kernel_launch(void* const* d_in, const int* in_sizes, int n_in,
                              void* d_out, int out_size, void* d_ws, size_t ws_size,
                              hipStream_t stream) {
    const float* cl     = (const float*)d_in[0];
    const float* cd     = (const float*)d_in[1];
    const float* re_log = (const float*)d_in[2];
    const float* mach   = (const float*)d_in[3];
    const float* alpha  = (const float*)d_in[4];
    const float* u      = (const float*)d_in[5];
    const float* We     = (const float*)d_in[6];
    const float* be     = (const float*)d_in[7];
    const float* Bmat   = (const float*)d_in[8];
    const float* Wproj  = (const float*)d_in[9];
    const float* bproj  = (const float*)d_in[10];
    const float* Wr1    = (const float*)d_in[11];
    const float* br1    = (const float*)d_in[12];
    const float* Wr2    = (const float*)d_in[13];
    const float* br2    = (const float*)d_in[14];
    const float* ln_g   = (const float*)d_in[15];
    const float* ln_b   = (const float*)d_in[16];
    const float* Wout   = (const float*)d_in[17];
    const float* bout   = (const float*)d_in[18];
    const float* fg     = (const float*)d_in[19];
    const float* fb     = (const float*)d_in[20];
    const float* Wcst   = (const float*)d_in[21];
    const float* bcst   = (const float*)d_in[22];
    const float* Wcl    = (const float*)d_in[23];
    const float* bcl    = (const float*)d_in[24];

    float* Cpre = (float*)d_ws;   // 96 floats (n-paired layout)
    const int B = in_sizes[0];

    hipLaunchKernelGGL(precompute_C_kernel, dim3(1), dim3(128), 0, stream,
                       Bmat, Wproj, bproj, Cpre);

    const int blocks = (B + 255) / 256;
    hipLaunchKernelGGL(whisp_kernel, dim3(blocks), dim3(256), 0, stream,
                       cl, cd, re_log, mach, alpha, u, We, be, Wproj,
                       Wr1, br1, Wr2, br2, ln_g, ln_b, Wout, bout, fg, fb,
                       Wcst, bcst, Wcl, bcl, Cpre, (float*)d_out, B);
}